// Round 1
// baseline (502.654 us; speedup 1.0000x reference)
//
#include <hip/hip_runtime.h>
#include <math.h>

#define HH 2048
#define WW 2048
#define TT 11
constexpr long long HW = (long long)HH * WW;

struct MMat { float m[TT][TT]; };

// ---------------- phy kernel: interior residual sum of squares ----------------
__global__ __launch_bounds__(256) void phy_kernel(const float* __restrict__ u,
                                                  const float* __restrict__ f1,
                                                  MMat M,
                                                  float* __restrict__ ws)
{
    __shared__ float tile[10][34];
    const int tx = threadIdx.x;           // 0..31
    const int ty = threadIdx.y;           // 0..7
    const int tid = ty * 32 + tx;
    const int w0 = 1 + blockIdx.x * 32;   // first interior col of this tile
    const int h0 = 1 + blockIdx.y * 8;    // first interior row of this tile
    const int hh = h0 + ty;
    const int wcol = w0 + tx;
    const bool valid = (hh <= HH - 2) && (wcol <= WW - 2);

    float uc[TT];
    float lap[TT];

    const float c0 = 0.34520446044393f;
    const float c1 = 0.309591078922457f;
    const float c2 = -2.619182157203629f;

    for (int s = 0; s < TT; ++s) {
        // cooperative load of 10x34 halo tile (clamped coords; clamped lanes are
        // only consumed by invalid pixels, value irrelevant but must not fault)
        for (int idx = tid; idx < 340; idx += 256) {
            int r = idx / 34;
            int c = idx - r * 34;
            int gh = h0 - 1 + r; if (gh > HH - 1) gh = HH - 1;
            int gw = w0 - 1 + c; if (gw > WW - 1) gw = WW - 1;
            tile[r][c] = u[(long long)s * HW + (long long)gh * WW + gw];
        }
        __syncthreads();
        float a00 = tile[ty][tx],     a01 = tile[ty][tx + 1],     a02 = tile[ty][tx + 2];
        float a10 = tile[ty + 1][tx], a11 = tile[ty + 1][tx + 1], a12 = tile[ty + 1][tx + 2];
        float a20 = tile[ty + 2][tx], a21 = tile[ty + 2][tx + 1], a22 = tile[ty + 2][tx + 2];
        uc[s] = a11;
        lap[s] = c0 * ((a00 + a02) + (a20 + a22))
               + c1 * ((a01 + a21) + (a10 + a12))
               + c2 * a11;
        __syncthreads();
    }

    float acc = 0.0f;
    if (valid) {
        const float kod = 0.01f * 4194304.0f;   // KAPPA / DX^2
        const long long pix = (long long)hh * WW + wcol;
        #pragma unroll
        for (int t = 0; t < TT; ++t) {
            float D = 0.0f;
            #pragma unroll
            for (int s = 0; s < TT; ++s) D += M.m[t][s] * uc[s];
            float f1v = f1[(long long)t * HW + pix];
            float fu = D - kod * lap[t] + uc[t] - f1v;
            acc += fu * fu;
        }
    }

    // 3-level reduction: wave shuffle -> LDS -> one atomic per block
    #pragma unroll
    for (int off = 32; off > 0; off >>= 1)
        acc += __shfl_down(acc, off, 64);
    __shared__ float wsum[4];
    int lane = tid & 63, wid = tid >> 6;
    if (lane == 0) wsum[wid] = acc;
    __syncthreads();
    if (tid == 0) {
        float s = (wsum[0] + wsum[1]) + (wsum[2] + wsum[3]);
        atomicAdd(&ws[0], s);
    }
}

// ---------------- bc kernel: boundary loss ----------------
__global__ __launch_bounds__(256) void bc_kernel(const float* __restrict__ u,
                                                 float* __restrict__ ws)
{
    int idx = blockIdx.x * 256 + threadIdx.x;   // 0 .. 10*2048-1
    float acc = 0.0f;
    if (idx < 10 * 2048) {
        int i = idx >> 11;       // time index 0..9 (u slice i+1)
        int j = idx & 2047;
        float tval = 0.1f + 0.1f * (float)i;               // linspace(0.1,1.0,10)
        float xj = (float)j * (1.0f / 2047.0f);            // linspace(0,1,2048)
        float x1 = powf(tval, 1.5f) * sinf(6.283185307179586f * xj);
        const float* ub = u + (long long)(i + 1) * HW;
        float l = ub[(long long)j * WW + 0]        - x1;
        float r = ub[(long long)j * WW + (WW - 1)] - x1;
        float tp = ub[j]                            - x1;
        float bt = ub[(long long)(HH - 1) * WW + j] - x1;
        acc = l * l + r * r + tp * tp + bt * bt;
    }
    #pragma unroll
    for (int off = 32; off > 0; off >>= 1)
        acc += __shfl_down(acc, off, 64);
    __shared__ float wsum[4];
    int tid = threadIdx.x;
    int lane = tid & 63, wid = tid >> 6;
    if (lane == 0) wsum[wid] = acc;
    __syncthreads();
    if (tid == 0) {
        float s = (wsum[0] + wsum[1]) + (wsum[2] + wsum[3]);
        atomicAdd(&ws[1], s);
    }
}

// ---------------- finalize ----------------
__global__ void fin_kernel(const float* __restrict__ ws, float* __restrict__ out)
{
    // phy = 2 * sum / (11*2046*2046)
    out[0] = ws[0] * (2.0f / (11.0f * 2046.0f * 2046.0f));
    // bc = sum / (10*2048) / 2048
    out[1] = ws[1] * (1.0f / (10.0f * 2048.0f * 2048.0f));
}

static MMat make_M()
{
    double w[10];
    w[0] = 1.0;
    for (int j = 1; j <= 9; ++j)
        w[j] = pow((double)j + 1.0, 0.5) - pow((double)j, 0.5);
    double M[TT][TT] = {};
    for (int i = 1; i < TT; ++i) {
        M[i][i] = w[0];
        M[i][0] -= w[i - 1];
        for (int k = 1; k < i; ++k)
            M[i][k] = -(w[i - k - 1] - w[i - k]);
    }
    double pref = pow(0.1, -0.5) / 0.886226925452758;
    MMat r;
    for (int i = 0; i < TT; ++i)
        for (int j = 0; j < TT; ++j)
            r.m[i][j] = (float)(pref * M[i][j]);
    return r;
}

extern "C" void kernel_launch(void* const* d_in, const int* in_sizes, int n_in,
                              void* d_out, int out_size, void* d_ws, size_t ws_size,
                              hipStream_t stream)
{
    const float* u  = (const float*)d_in[0];
    const float* f1 = (const float*)d_in[1];
    float* out = (float*)d_out;
    float* ws  = (float*)d_ws;

    MMat M = make_M();

    hipMemsetAsync(ws, 0, 2 * sizeof(float), stream);

    dim3 block(32, 8);
    dim3 grid(64, 256);   // 64*32 >= 2046 cols, 256*8 >= 2046 rows
    phy_kernel<<<grid, block, 0, stream>>>(u, f1, M, ws);

    bc_kernel<<<(10 * 2048 + 255) / 256, 256, 0, stream>>>(u, ws);

    fin_kernel<<<1, 1, 0, stream>>>(ws, out);
}

// Round 2
// 468.078 us; speedup vs baseline: 1.0739x; 1.0739x over previous
//
#include <hip/hip_runtime.h>
#include <math.h>

#define HH 2048
#define WW 2048
#define TT 11
constexpr long long HW = (long long)HH * WW;

struct MMat { float m[TT][TT]; };

// ---------------- phy kernel: interior residual sum of squares ----------------
// Block: 64 lanes (x) * 4 rows (y). Each thread: float4 = 4 consecutive cols.
// Wave = one row segment of 256 cols -> horizontal neighbors via shuffles.
// No LDS staging, no barriers until final reduction.
__global__ __launch_bounds__(256) void phy_kernel(const float* __restrict__ u,
                                                  const float* __restrict__ f1,
                                                  MMat M,
                                                  float* __restrict__ ws)
{
    const int lane = threadIdx.x;              // 0..63
    const int ty   = threadIdx.y;              // 0..3
    const int c    = blockIdx.x * 64 + lane;   // float4 index 0..511
    const int h    = 1 + blockIdx.y * 4 + ty;  // 1..2048
    const int heff = (h > HH - 2) ? (HH - 2) : h;
    const float rowmask = (h <= HH - 2) ? 1.0f : 0.0f;

    float4 mask;
    mask.x = (c == 0)   ? 0.0f : rowmask;   // col 0 is boundary
    mask.y = rowmask;
    mask.z = rowmask;
    mask.w = (c == 511) ? 0.0f : rowmask;   // col 2047 is boundary

    const long long rowm = (long long)(heff - 1) * WW;
    const long long row0 = (long long)heff * WW;
    const long long rowp = (long long)(heff + 1) * WW;
    const int col4 = c * 4;
    const int cl = (col4 - 1 < 0) ? 0 : col4 - 1;
    const int cr = (col4 + 4 > WW - 1) ? (WW - 1) : col4 + 4;

    const float c0 = 0.34520446044393f;
    const float c1 = 0.309591078922457f;
    const float c2 = -2.619182157203629f;
    const float kod = 0.01f * 4194304.0f;   // KAPPA / DX^2

    float4 uc[TT];   // center values per slice
    float4 B[TT];    // uc - kod*lap - f1 per slice

    #pragma unroll
    for (int s = 0; s < TT; ++s) {
        const float* up = u + (long long)s * HW;
        const float4 vm = *(const float4*)(up + rowm + col4);
        const float4 v0 = *(const float4*)(up + row0 + col4);
        const float4 vp = *(const float4*)(up + rowp + col4);
        const float4 fv = *(const float4*)(f1 + (long long)s * HW + row0 + col4);

        float lm = __shfl_up(vm.w, 1);
        float l0 = __shfl_up(v0.w, 1);
        float lp = __shfl_up(vp.w, 1);
        float rm = __shfl_down(vm.x, 1);
        float r0 = __shfl_down(v0.x, 1);
        float rp = __shfl_down(vp.x, 1);
        if (lane == 0)  { lm = up[rowm + cl]; l0 = up[row0 + cl]; lp = up[rowp + cl]; }
        if (lane == 63) { rm = up[rowm + cr]; r0 = up[row0 + cr]; rp = up[rowp + cr]; }

        float4 lap;
        lap.x = c0 * ((lm   + vm.y) + (lp   + vp.y)) + c1 * ((vm.x + vp.x) + (l0   + v0.y)) + c2 * v0.x;
        lap.y = c0 * ((vm.x + vm.z) + (vp.x + vp.z)) + c1 * ((vm.y + vp.y) + (v0.x + v0.z)) + c2 * v0.y;
        lap.z = c0 * ((vm.y + vm.w) + (vp.y + vp.w)) + c1 * ((vm.z + vp.z) + (v0.y + v0.w)) + c2 * v0.z;
        lap.w = c0 * ((vm.z + rm  ) + (vp.z + rp  )) + c1 * ((vm.w + vp.w) + (v0.z + r0  )) + c2 * v0.w;

        uc[s] = v0;
        B[s].x = v0.x - kod * lap.x - fv.x;
        B[s].y = v0.y - kod * lap.y - fv.y;
        B[s].z = v0.z - kod * lap.z - fv.z;
        B[s].w = v0.w - kod * lap.w - fv.w;
    }

    float4 acc4 = make_float4(0.0f, 0.0f, 0.0f, 0.0f);
    #pragma unroll
    for (int t = 0; t < TT; ++t) {
        float4 D = make_float4(0.0f, 0.0f, 0.0f, 0.0f);
        #pragma unroll
        for (int s = 0; s <= t; ++s) {   // M is strictly lower-triangular (M[t][s]=0 for s>t)
            const float m = M.m[t][s];
            D.x += m * uc[s].x;
            D.y += m * uc[s].y;
            D.z += m * uc[s].z;
            D.w += m * uc[s].w;
        }
        float fx = (D.x + B[t].x) * mask.x;
        float fy = (D.y + B[t].y) * mask.y;
        float fz = (D.z + B[t].z) * mask.z;
        float fw = (D.w + B[t].w) * mask.w;
        acc4.x += fx * fx;
        acc4.y += fy * fy;
        acc4.z += fz * fz;
        acc4.w += fw * fw;
    }

    float acc = (acc4.x + acc4.y) + (acc4.z + acc4.w);

    // 3-level reduction: wave shuffle -> LDS -> one atomic per block
    #pragma unroll
    for (int off = 32; off > 0; off >>= 1)
        acc += __shfl_down(acc, off, 64);
    __shared__ float wsum[4];
    const int tid = ty * 64 + lane;
    const int wid = tid >> 6;
    if (lane == 0) wsum[wid] = acc;
    __syncthreads();
    if (tid == 0) {
        float s = (wsum[0] + wsum[1]) + (wsum[2] + wsum[3]);
        atomicAdd(&ws[0], s);
    }
}

// ---------------- bc kernel: boundary loss ----------------
__global__ __launch_bounds__(256) void bc_kernel(const float* __restrict__ u,
                                                 float* __restrict__ ws)
{
    int idx = blockIdx.x * 256 + threadIdx.x;   // 0 .. 10*2048-1
    float acc = 0.0f;
    if (idx < 10 * 2048) {
        int i = idx >> 11;       // time index 0..9 (u slice i+1)
        int j = idx & 2047;
        float tval = 0.1f + 0.1f * (float)i;               // linspace(0.1,1.0,10)
        float xj = (float)j * (1.0f / 2047.0f);            // linspace(0,1,2048)
        float x1 = powf(tval, 1.5f) * sinf(6.283185307179586f * xj);
        const float* ub = u + (long long)(i + 1) * HW;
        float l = ub[(long long)j * WW + 0]        - x1;
        float r = ub[(long long)j * WW + (WW - 1)] - x1;
        float tp = ub[j]                            - x1;
        float bt = ub[(long long)(HH - 1) * WW + j] - x1;
        acc = l * l + r * r + tp * tp + bt * bt;
    }
    #pragma unroll
    for (int off = 32; off > 0; off >>= 1)
        acc += __shfl_down(acc, off, 64);
    __shared__ float wsum[4];
    int tid = threadIdx.x;
    int lane = tid & 63, wid = tid >> 6;
    if (lane == 0) wsum[wid] = acc;
    __syncthreads();
    if (tid == 0) {
        float s = (wsum[0] + wsum[1]) + (wsum[2] + wsum[3]);
        atomicAdd(&ws[1], s);
    }
}

// ---------------- finalize ----------------
__global__ void fin_kernel(const float* __restrict__ ws, float* __restrict__ out)
{
    out[0] = ws[0] * (2.0f / (11.0f * 2046.0f * 2046.0f));
    out[1] = ws[1] * (1.0f / (10.0f * 2048.0f * 2048.0f));
}

static MMat make_M()
{
    double w[10];
    w[0] = 1.0;
    for (int j = 1; j <= 9; ++j)
        w[j] = pow((double)j + 1.0, 0.5) - pow((double)j, 0.5);
    double M[TT][TT] = {};
    for (int i = 1; i < TT; ++i) {
        M[i][i] = w[0];
        M[i][0] -= w[i - 1];
        for (int k = 1; k < i; ++k)
            M[i][k] = -(w[i - k - 1] - w[i - k]);
    }
    double pref = pow(0.1, -0.5) / 0.886226925452758;
    MMat r;
    for (int i = 0; i < TT; ++i)
        for (int j = 0; j < TT; ++j)
            r.m[i][j] = (float)(pref * M[i][j]);
    return r;
}

extern "C" void kernel_launch(void* const* d_in, const int* in_sizes, int n_in,
                              void* d_out, int out_size, void* d_ws, size_t ws_size,
                              hipStream_t stream)
{
    const float* u  = (const float*)d_in[0];
    const float* f1 = (const float*)d_in[1];
    float* out = (float*)d_out;
    float* ws  = (float*)d_ws;

    MMat M = make_M();

    hipMemsetAsync(ws, 0, 2 * sizeof(float), stream);

    dim3 block(64, 4);
    dim3 grid(8, 512);   // 8*64*4 = 2048 float4-cols, 512*4 = 2048 rows (masked to interior)
    phy_kernel<<<grid, block, 0, stream>>>(u, f1, M, ws);

    bc_kernel<<<(10 * 2048 + 255) / 256, 256, 0, stream>>>(u, ws);

    fin_kernel<<<1, 1, 0, stream>>>(ws, out);
}

// Round 3
// 377.691 us; speedup vs baseline: 1.3309x; 1.2393x over previous
//
#include <hip/hip_runtime.h>
#include <math.h>

#define HH 2048
#define WW 2048
#define TT 11
constexpr long long HW = (long long)HH * WW;

struct MMat { float m[TT][TT]; };

__device__ __forceinline__ float4 ld4(const float* p) { return *(const float4*)p; }

// ---------------- phy kernel ----------------
// 64 lanes (x) * 4 rows (y); each thread = 4 consecutive cols of one row.
// No LDS staging, no shuffles, no divergence: horizontal neighbors come from
// clamped scalar loads (L1 hits). M is lower-triangular -> accumulate D[t]
// on the fly; D[s] completes at slice s and is squared+retired immediately,
// so long-lived state is <=44 regs with shrinking liveness.
__global__ __launch_bounds__(256, 4) void phy_kernel(const float* __restrict__ u,
                                                     const float* __restrict__ f1,
                                                     MMat M,
                                                     float* __restrict__ ws)
{
    const int lane = threadIdx.x;              // 0..63
    const int ty   = threadIdx.y;              // 0..3
    const int c    = blockIdx.x * 64 + lane;   // float4 group 0..511
    const int h    = 1 + blockIdx.y * 4 + ty;  // 1..2048
    const int heff = (h > HH - 2) ? (HH - 2) : h;
    const float rowmask = (h <= HH - 2) ? 1.0f : 0.0f;

    const float mx = (c == 0)   ? 0.0f : rowmask;
    const float my = rowmask;
    const float mz = rowmask;
    const float mw = (c == 511) ? 0.0f : rowmask;

    const long long rowm = (long long)(heff - 1) * WW;
    const long long row0 = (long long)heff * WW;
    const long long rowp = (long long)(heff + 1) * WW;
    const int col4 = c * 4;
    const int cl = (col4 - 1 < 0) ? 0 : col4 - 1;        // clamped: garbage only feeds masked lanes
    const int cr = (col4 + 4 > WW - 1) ? (WW - 1) : col4 + 4;

    const float c0 = 0.34520446044393f;
    const float c1 = 0.309591078922457f;
    const float c2 = -2.619182157203629f;
    const float kod = 0.01f * 4194304.0f;   // KAPPA / DX^2

    float4 D[TT];
    #pragma unroll
    for (int t = 0; t < TT; ++t) D[t] = make_float4(0.f, 0.f, 0.f, 0.f);

    float acc = 0.0f;

    #pragma unroll
    for (int s = 0; s < TT; ++s) {
        const float* up = u + (long long)s * HW;
        const float4 vm = ld4(up + rowm + col4);
        const float4 v0 = ld4(up + row0 + col4);
        const float4 vp = ld4(up + rowp + col4);
        const float  lm = up[rowm + cl];
        const float  l0 = up[row0 + cl];
        const float  lp = up[rowp + cl];
        const float  rm = up[rowm + cr];
        const float  r0 = up[row0 + cr];
        const float  rp = up[rowp + cr];
        const float4 fv = ld4(f1 + (long long)s * HW + row0 + col4);

        float4 lap;
        lap.x = c0 * ((lm   + vm.y) + (lp   + vp.y)) + c1 * ((vm.x + vp.x) + (l0   + v0.y)) + c2 * v0.x;
        lap.y = c0 * ((vm.x + vm.z) + (vp.x + vp.z)) + c1 * ((vm.y + vp.y) + (v0.x + v0.z)) + c2 * v0.y;
        lap.z = c0 * ((vm.y + vm.w) + (vp.y + vp.w)) + c1 * ((vm.z + vp.z) + (v0.y + v0.w)) + c2 * v0.z;
        lap.w = c0 * ((vm.z + rm  ) + (vp.z + rp  )) + c1 * ((vm.w + vp.w) + (v0.z + r0  )) + c2 * v0.w;

        // fu[s] = D[s] (partials from s'<s) + M[s][s]*u_s + (u_s - kod*lap - f1)
        const float mss = M.m[s][s];
        float fx = (D[s].x + mss * v0.x + (v0.x - kod * lap.x - fv.x)) * mx;
        float fy = (D[s].y + mss * v0.y + (v0.y - kod * lap.y - fv.y)) * my;
        float fz = (D[s].z + mss * v0.z + (v0.z - kod * lap.z - fv.z)) * mz;
        float fw = (D[s].w + mss * v0.w + (v0.w - kod * lap.w - fv.w)) * mw;
        acc += fx * fx + fy * fy + fz * fz + fw * fw;

        // push this slice's contribution into future accumulators (t > s)
        #pragma unroll
        for (int t = s + 1; t < TT; ++t) {
            const float m = M.m[t][s];
            D[t].x += m * v0.x;
            D[t].y += m * v0.y;
            D[t].z += m * v0.z;
            D[t].w += m * v0.w;
        }
    }

    // 3-level reduction: wave shuffle -> LDS -> one atomic per block
    #pragma unroll
    for (int off = 32; off > 0; off >>= 1)
        acc += __shfl_down(acc, off, 64);
    __shared__ float wsum[4];
    const int tid = ty * 64 + lane;
    const int wid = tid >> 6;
    if (lane == 0) wsum[wid] = acc;
    __syncthreads();
    if (tid == 0) {
        float s = (wsum[0] + wsum[1]) + (wsum[2] + wsum[3]);
        atomicAdd(&ws[0], s);
    }
}

// ---------------- bc kernel: boundary loss ----------------
__global__ __launch_bounds__(256) void bc_kernel(const float* __restrict__ u,
                                                 float* __restrict__ ws)
{
    int idx = blockIdx.x * 256 + threadIdx.x;   // 0 .. 10*2048-1
    float acc = 0.0f;
    if (idx < 10 * 2048) {
        int i = idx >> 11;       // time index 0..9 (u slice i+1)
        int j = idx & 2047;
        float tval = 0.1f + 0.1f * (float)i;
        float xj = (float)j * (1.0f / 2047.0f);
        float x1 = powf(tval, 1.5f) * sinf(6.283185307179586f * xj);
        const float* ub = u + (long long)(i + 1) * HW;
        float l = ub[(long long)j * WW + 0]        - x1;
        float r = ub[(long long)j * WW + (WW - 1)] - x1;
        float tp = ub[j]                            - x1;
        float bt = ub[(long long)(HH - 1) * WW + j] - x1;
        acc = l * l + r * r + tp * tp + bt * bt;
    }
    #pragma unroll
    for (int off = 32; off > 0; off >>= 1)
        acc += __shfl_down(acc, off, 64);
    __shared__ float wsum[4];
    int tid = threadIdx.x;
    int lane = tid & 63, wid = tid >> 6;
    if (lane == 0) wsum[wid] = acc;
    __syncthreads();
    if (tid == 0) {
        float s = (wsum[0] + wsum[1]) + (wsum[2] + wsum[3]);
        atomicAdd(&ws[1], s);
    }
}

// ---------------- finalize ----------------
__global__ void fin_kernel(const float* __restrict__ ws, float* __restrict__ out)
{
    out[0] = ws[0] * (2.0f / (11.0f * 2046.0f * 2046.0f));
    out[1] = ws[1] * (1.0f / (10.0f * 2048.0f * 2048.0f));
}

static MMat make_M()
{
    double w[10];
    w[0] = 1.0;
    for (int j = 1; j <= 9; ++j)
        w[j] = pow((double)j + 1.0, 0.5) - pow((double)j, 0.5);
    double M[TT][TT] = {};
    for (int i = 1; i < TT; ++i) {
        M[i][i] = w[0];
        M[i][0] -= w[i - 1];
        for (int k = 1; k < i; ++k)
            M[i][k] = -(w[i - k - 1] - w[i - k]);
    }
    double pref = pow(0.1, -0.5) / 0.886226925452758;
    MMat r;
    for (int i = 0; i < TT; ++i)
        for (int j = 0; j < TT; ++j)
            r.m[i][j] = (float)(pref * M[i][j]);
    return r;
}

extern "C" void kernel_launch(void* const* d_in, const int* in_sizes, int n_in,
                              void* d_out, int out_size, void* d_ws, size_t ws_size,
                              hipStream_t stream)
{
    const float* u  = (const float*)d_in[0];
    const float* f1 = (const float*)d_in[1];
    float* out = (float*)d_out;
    float* ws  = (float*)d_ws;

    MMat M = make_M();

    hipMemsetAsync(ws, 0, 2 * sizeof(float), stream);

    dim3 block(64, 4);
    dim3 grid(8, 512);
    phy_kernel<<<grid, block, 0, stream>>>(u, f1, M, ws);

    bc_kernel<<<(10 * 2048 + 255) / 256, 256, 0, stream>>>(u, ws);

    fin_kernel<<<1, 1, 0, stream>>>(ws, out);
}

// Round 4
// 374.551 us; speedup vs baseline: 1.3420x; 1.0084x over previous
//
#include <hip/hip_runtime.h>
#include <math.h>

#define HH 2048
#define WW 2048
#define TT 11
constexpr long long HW = (long long)HH * WW;

struct MMat { float m[TT][TT]; };

__device__ __forceinline__ float4 ld4(const float* p) { return *(const float4*)p; }

// ---------------- phy kernel ----------------
// Overlapped-window scheme: each wave loads an aligned 256-col window
// (64 lanes x float4) but outputs only cols [252*bx+1 .. 252*bx+252]
// (clamped at the right edge; coverage exact & disjoint via masks).
// All horizontal stencil neighbors are in-window: in-register or one
// __shfl by 1. Zero scattered loads, zero divergence.
// M lower-triangular -> D[t] accumulated on the fly (low VGPR).
__global__ __launch_bounds__(256, 4) void phy_kernel(const float* __restrict__ u,
                                                     const float* __restrict__ f1,
                                                     MMat M,
                                                     float* __restrict__ ws)
{
    const int lane = threadIdx.x;              // 0..63
    const int ty   = threadIdx.y;              // 0..3
    const int bx   = blockIdx.x;               // 0..8
    int w0 = bx * 252; if (w0 > WW - 256) w0 = WW - 256;   // aligned window start
    const int lo = bx * 252 + 1;               // first output col of this window
    int hi = bx * 252 + 252; if (hi > WW - 2) hi = WW - 2; // last output col

    const int h    = 1 + blockIdx.y * 4 + ty;  // 1..2048
    const int heff = (h > HH - 2) ? (HH - 2) : h;
    const float rowmask = (h <= HH - 2) ? 1.0f : 0.0f;

    const int col0 = w0 + lane * 4;            // absolute col of element .x
    float4 mask;
    {
        int c0 = col0, c1 = col0 + 1, c2 = col0 + 2, c3 = col0 + 3;
        mask.x = (c0 >= lo && c0 <= hi) ? rowmask : 0.0f;
        mask.y = (c1 >= lo && c1 <= hi) ? rowmask : 0.0f;
        mask.z = (c2 >= lo && c2 <= hi) ? rowmask : 0.0f;
        mask.w = (c3 >= lo && c3 <= hi) ? rowmask : 0.0f;
    }

    const long long rowm = (long long)(heff - 1) * WW + col0;
    const long long row0 = (long long)heff * WW + col0;
    const long long rowp = (long long)(heff + 1) * WW + col0;

    const float c0f = 0.34520446044393f;
    const float c1f = 0.309591078922457f;
    const float c2f = -2.619182157203629f;
    const float kod = 0.01f * 4194304.0f;   // KAPPA / DX^2

    float4 D[TT];
    #pragma unroll
    for (int t = 0; t < TT; ++t) D[t] = make_float4(0.f, 0.f, 0.f, 0.f);

    float acc = 0.0f;

    #pragma unroll
    for (int s = 0; s < TT; ++s) {
        const float* up = u + (long long)s * HW;
        const float4 vm = ld4(up + rowm);
        const float4 v0 = ld4(up + row0);
        const float4 vp = ld4(up + rowp);
        const float4 fv = ld4(f1 + (long long)s * HW + row0);

        // in-wave horizontal neighbors (window pos 0 / 255 never output -> garbage safe)
        const float lm = __shfl_up(vm.w, 1);
        const float l0 = __shfl_up(v0.w, 1);
        const float lp = __shfl_up(vp.w, 1);
        const float rm = __shfl_down(vm.x, 1);
        const float r0 = __shfl_down(v0.x, 1);
        const float rp = __shfl_down(vp.x, 1);

        float4 lap;
        lap.x = c0f * ((lm   + vm.y) + (lp   + vp.y)) + c1f * ((vm.x + vp.x) + (l0   + v0.y)) + c2f * v0.x;
        lap.y = c0f * ((vm.x + vm.z) + (vp.x + vp.z)) + c1f * ((vm.y + vp.y) + (v0.x + v0.z)) + c2f * v0.y;
        lap.z = c0f * ((vm.y + vm.w) + (vp.y + vp.w)) + c1f * ((vm.z + vp.z) + (v0.y + v0.w)) + c2f * v0.z;
        lap.w = c0f * ((vm.z + rm  ) + (vp.z + rp  )) + c1f * ((vm.w + vp.w) + (v0.z + r0  )) + c2f * v0.w;

        // fu[s] = D[s] (partials s'<s) + M[s][s]*u_s + (u_s - kod*lap - f1)
        const float mss = M.m[s][s];
        float fx = (D[s].x + mss * v0.x + (v0.x - kod * lap.x - fv.x)) * mask.x;
        float fy = (D[s].y + mss * v0.y + (v0.y - kod * lap.y - fv.y)) * mask.y;
        float fz = (D[s].z + mss * v0.z + (v0.z - kod * lap.z - fv.z)) * mask.z;
        float fw = (D[s].w + mss * v0.w + (v0.w - kod * lap.w - fv.w)) * mask.w;
        acc += fx * fx + fy * fy + fz * fz + fw * fw;

        #pragma unroll
        for (int t = s + 1; t < TT; ++t) {
            const float m = M.m[t][s];
            D[t].x += m * v0.x;
            D[t].y += m * v0.y;
            D[t].z += m * v0.z;
            D[t].w += m * v0.w;
        }
    }

    // 3-level reduction: wave shuffle -> LDS -> one atomic per block
    #pragma unroll
    for (int off = 32; off > 0; off >>= 1)
        acc += __shfl_down(acc, off, 64);
    __shared__ float wsum[4];
    const int tid = ty * 64 + lane;
    const int wid = tid >> 6;
    if (lane == 0) wsum[wid] = acc;
    __syncthreads();
    if (tid == 0) {
        float s = (wsum[0] + wsum[1]) + (wsum[2] + wsum[3]);
        atomicAdd(&ws[0], s);
    }
}

// ---------------- bc kernel: boundary loss ----------------
__global__ __launch_bounds__(256) void bc_kernel(const float* __restrict__ u,
                                                 float* __restrict__ ws)
{
    int idx = blockIdx.x * 256 + threadIdx.x;   // 0 .. 10*2048-1
    float acc = 0.0f;
    if (idx < 10 * 2048) {
        int i = idx >> 11;       // time index 0..9 (u slice i+1)
        int j = idx & 2047;
        float tval = 0.1f + 0.1f * (float)i;
        float xj = (float)j * (1.0f / 2047.0f);
        float x1 = powf(tval, 1.5f) * sinf(6.283185307179586f * xj);
        const float* ub = u + (long long)(i + 1) * HW;
        float l = ub[(long long)j * WW + 0]        - x1;
        float r = ub[(long long)j * WW + (WW - 1)] - x1;
        float tp = ub[j]                            - x1;
        float bt = ub[(long long)(HH - 1) * WW + j] - x1;
        acc = l * l + r * r + tp * tp + bt * bt;
    }
    #pragma unroll
    for (int off = 32; off > 0; off >>= 1)
        acc += __shfl_down(acc, off, 64);
    __shared__ float wsum[4];
    int tid = threadIdx.x;
    int lane = tid & 63, wid = tid >> 6;
    if (lane == 0) wsum[wid] = acc;
    __syncthreads();
    if (tid == 0) {
        float s = (wsum[0] + wsum[1]) + (wsum[2] + wsum[3]);
        atomicAdd(&ws[1], s);
    }
}

// ---------------- finalize ----------------
__global__ void fin_kernel(const float* __restrict__ ws, float* __restrict__ out)
{
    out[0] = ws[0] * (2.0f / (11.0f * 2046.0f * 2046.0f));
    out[1] = ws[1] * (1.0f / (10.0f * 2048.0f * 2048.0f));
}

static MMat make_M()
{
    double w[10];
    w[0] = 1.0;
    for (int j = 1; j <= 9; ++j)
        w[j] = pow((double)j + 1.0, 0.5) - pow((double)j, 0.5);
    double M[TT][TT] = {};
    for (int i = 1; i < TT; ++i) {
        M[i][i] = w[0];
        M[i][0] -= w[i - 1];
        for (int k = 1; k < i; ++k)
            M[i][k] = -(w[i - k - 1] - w[i - k]);
    }
    double pref = pow(0.1, -0.5) / 0.886226925452758;
    MMat r;
    for (int i = 0; i < TT; ++i)
        for (int j = 0; j < TT; ++j)
            r.m[i][j] = (float)(pref * M[i][j]);
    return r;
}

extern "C" void kernel_launch(void* const* d_in, const int* in_sizes, int n_in,
                              void* d_out, int out_size, void* d_ws, size_t ws_size,
                              hipStream_t stream)
{
    const float* u  = (const float*)d_in[0];
    const float* f1 = (const float*)d_in[1];
    float* out = (float*)d_out;
    float* ws  = (float*)d_ws;

    MMat M = make_M();

    hipMemsetAsync(ws, 0, 2 * sizeof(float), stream);

    dim3 block(64, 4);
    dim3 grid(9, 512);   // 9 col-windows (252 output cols each), 512*4 = 2048 rows
    phy_kernel<<<grid, block, 0, stream>>>(u, f1, M, ws);

    bc_kernel<<<(10 * 2048 + 255) / 256, 256, 0, stream>>>(u, ws);

    fin_kernel<<<1, 1, 0, stream>>>(ws, out);
}

// Round 5
// 374.103 us; speedup vs baseline: 1.3436x; 1.0012x over previous
//
#include <hip/hip_runtime.h>
#include <math.h>

#define HH 2048
#define WW 2048
#define TT 11
constexpr long long HW = (long long)HH * WW;

struct MMat { float m[TT][TT]; };

__device__ __forceinline__ float4 ld4(const float* p) { return *(const float4*)p; }

// ---------------- phy kernel ----------------
// Overlapped-window scheme (R4) + explicit 2-deep software pipeline over the
// 11 time slices: slice s+1's four float4 loads are issued before slice s is
// consumed, so each slice's memory latency hides behind the previous slice's
// shuffles+compute instead of serializing 11 round trips per wave.
__global__ __launch_bounds__(256, 4) void phy_kernel(const float* __restrict__ u,
                                                     const float* __restrict__ f1,
                                                     MMat M,
                                                     float* __restrict__ ws)
{
    const int lane = threadIdx.x;              // 0..63
    const int ty   = threadIdx.y;              // 0..3
    const int bx   = blockIdx.x;               // 0..8
    int w0 = bx * 252; if (w0 > WW - 256) w0 = WW - 256;   // aligned window start
    const int lo = bx * 252 + 1;               // first output col of this window
    int hi = bx * 252 + 252; if (hi > WW - 2) hi = WW - 2; // last output col

    const int h    = 1 + blockIdx.y * 4 + ty;  // 1..2048
    const int heff = (h > HH - 2) ? (HH - 2) : h;
    const float rowmask = (h <= HH - 2) ? 1.0f : 0.0f;

    const int col0 = w0 + lane * 4;            // absolute col of element .x
    float4 mask;
    {
        int c0 = col0, c1 = col0 + 1, c2 = col0 + 2, c3 = col0 + 3;
        mask.x = (c0 >= lo && c0 <= hi) ? rowmask : 0.0f;
        mask.y = (c1 >= lo && c1 <= hi) ? rowmask : 0.0f;
        mask.z = (c2 >= lo && c2 <= hi) ? rowmask : 0.0f;
        mask.w = (c3 >= lo && c3 <= hi) ? rowmask : 0.0f;
    }

    const long long rowm = (long long)(heff - 1) * WW + col0;
    const long long row0 = (long long)heff * WW + col0;
    const long long rowp = (long long)(heff + 1) * WW + col0;

    const float c0f = 0.34520446044393f;
    const float c1f = 0.309591078922457f;
    const float c2f = -2.619182157203629f;
    const float kod = 0.01f * 4194304.0f;   // KAPPA / DX^2

    float4 D[TT];
    #pragma unroll
    for (int t = 0; t < TT; ++t) D[t] = make_float4(0.f, 0.f, 0.f, 0.f);

    float acc = 0.0f;

    // pipeline prologue: slice 0 loads in flight
    float4 vm_n = ld4(u + rowm);
    float4 v0_n = ld4(u + row0);
    float4 vp_n = ld4(u + rowp);
    float4 fv_n = ld4(f1 + row0);

    #pragma unroll
    for (int s = 0; s < TT; ++s) {
        const float4 vm = vm_n;
        const float4 v0 = v0_n;
        const float4 vp = vp_n;
        const float4 fv = fv_n;

        // issue next slice's loads BEFORE consuming this slice
        if (s + 1 < TT) {
            const float* un = u + (long long)(s + 1) * HW;
            vm_n = ld4(un + rowm);
            v0_n = ld4(un + row0);
            vp_n = ld4(un + rowp);
            fv_n = ld4(f1 + (long long)(s + 1) * HW + row0);
        }

        // in-wave horizontal neighbors (window pos 0 / 255 never output -> garbage safe)
        const float lm = __shfl_up(vm.w, 1);
        const float l0 = __shfl_up(v0.w, 1);
        const float lp = __shfl_up(vp.w, 1);
        const float rm = __shfl_down(vm.x, 1);
        const float r0 = __shfl_down(v0.x, 1);
        const float rp = __shfl_down(vp.x, 1);

        float4 lap;
        lap.x = c0f * ((lm   + vm.y) + (lp   + vp.y)) + c1f * ((vm.x + vp.x) + (l0   + v0.y)) + c2f * v0.x;
        lap.y = c0f * ((vm.x + vm.z) + (vp.x + vp.z)) + c1f * ((vm.y + vp.y) + (v0.x + v0.z)) + c2f * v0.y;
        lap.z = c0f * ((vm.y + vm.w) + (vp.y + vp.w)) + c1f * ((vm.z + vp.z) + (v0.y + v0.w)) + c2f * v0.z;
        lap.w = c0f * ((vm.z + rm  ) + (vp.z + rp  )) + c1f * ((vm.w + vp.w) + (v0.z + r0  )) + c2f * v0.w;

        // fu[s] = D[s] (partials s'<s) + M[s][s]*u_s + (u_s - kod*lap - f1)
        const float mss = M.m[s][s];
        float fx = (D[s].x + mss * v0.x + (v0.x - kod * lap.x - fv.x)) * mask.x;
        float fy = (D[s].y + mss * v0.y + (v0.y - kod * lap.y - fv.y)) * mask.y;
        float fz = (D[s].z + mss * v0.z + (v0.z - kod * lap.z - fv.z)) * mask.z;
        float fw = (D[s].w + mss * v0.w + (v0.w - kod * lap.w - fv.w)) * mask.w;
        acc += fx * fx + fy * fy + fz * fz + fw * fw;

        #pragma unroll
        for (int t = s + 1; t < TT; ++t) {
            const float m = M.m[t][s];
            D[t].x += m * v0.x;
            D[t].y += m * v0.y;
            D[t].z += m * v0.z;
            D[t].w += m * v0.w;
        }
    }

    // 3-level reduction: wave shuffle -> LDS -> one atomic per block
    #pragma unroll
    for (int off = 32; off > 0; off >>= 1)
        acc += __shfl_down(acc, off, 64);
    __shared__ float wsum[4];
    const int tid = ty * 64 + lane;
    const int wid = tid >> 6;
    if (lane == 0) wsum[wid] = acc;
    __syncthreads();
    if (tid == 0) {
        float s = (wsum[0] + wsum[1]) + (wsum[2] + wsum[3]);
        atomicAdd(&ws[0], s);
    }
}

// ---------------- bc kernel: boundary loss ----------------
__global__ __launch_bounds__(256) void bc_kernel(const float* __restrict__ u,
                                                 float* __restrict__ ws)
{
    int idx = blockIdx.x * 256 + threadIdx.x;   // 0 .. 10*2048-1
    float acc = 0.0f;
    if (idx < 10 * 2048) {
        int i = idx >> 11;       // time index 0..9 (u slice i+1)
        int j = idx & 2047;
        float tval = 0.1f + 0.1f * (float)i;
        float xj = (float)j * (1.0f / 2047.0f);
        float x1 = powf(tval, 1.5f) * sinf(6.283185307179586f * xj);
        const float* ub = u + (long long)(i + 1) * HW;
        float l = ub[(long long)j * WW + 0]        - x1;
        float r = ub[(long long)j * WW + (WW - 1)] - x1;
        float tp = ub[j]                            - x1;
        float bt = ub[(long long)(HH - 1) * WW + j] - x1;
        acc = l * l + r * r + tp * tp + bt * bt;
    }
    #pragma unroll
    for (int off = 32; off > 0; off >>= 1)
        acc += __shfl_down(acc, off, 64);
    __shared__ float wsum[4];
    int tid = threadIdx.x;
    int lane = tid & 63, wid = tid >> 6;
    if (lane == 0) wsum[wid] = acc;
    __syncthreads();
    if (tid == 0) {
        float s = (wsum[0] + wsum[1]) + (wsum[2] + wsum[3]);
        atomicAdd(&ws[1], s);
    }
}

// ---------------- finalize ----------------
__global__ void fin_kernel(const float* __restrict__ ws, float* __restrict__ out)
{
    out[0] = ws[0] * (2.0f / (11.0f * 2046.0f * 2046.0f));
    out[1] = ws[1] * (1.0f / (10.0f * 2048.0f * 2048.0f));
}

static MMat make_M()
{
    double w[10];
    w[0] = 1.0;
    for (int j = 1; j <= 9; ++j)
        w[j] = pow((double)j + 1.0, 0.5) - pow((double)j, 0.5);
    double M[TT][TT] = {};
    for (int i = 1; i < TT; ++i) {
        M[i][i] = w[0];
        M[i][0] -= w[i - 1];
        for (int k = 1; k < i; ++k)
            M[i][k] = -(w[i - k - 1] - w[i - k]);
    }
    double pref = pow(0.1, -0.5) / 0.886226925452758;
    MMat r;
    for (int i = 0; i < TT; ++i)
        for (int j = 0; j < TT; ++j)
            r.m[i][j] = (float)(pref * M[i][j]);
    return r;
}

extern "C" void kernel_launch(void* const* d_in, const int* in_sizes, int n_in,
                              void* d_out, int out_size, void* d_ws, size_t ws_size,
                              hipStream_t stream)
{
    const float* u  = (const float*)d_in[0];
    const float* f1 = (const float*)d_in[1];
    float* out = (float*)d_out;
    float* ws  = (float*)d_ws;

    MMat M = make_M();

    hipMemsetAsync(ws, 0, 2 * sizeof(float), stream);

    dim3 block(64, 4);
    dim3 grid(9, 512);   // 9 col-windows (252 output cols each), 512*4 = 2048 rows
    phy_kernel<<<grid, block, 0, stream>>>(u, f1, M, ws);

    bc_kernel<<<(10 * 2048 + 255) / 256, 256, 0, stream>>>(u, ws);

    fin_kernel<<<1, 1, 0, stream>>>(ws, out);
}